// Round 18
// baseline (1018.512 us; speedup 1.0000x reference)
//
#include <hip/hip_runtime.h>
#include <hip/hip_bf16.h>
#include <stdint.h>

#define VOCAB 50257
#define VPAD3 51200   /* 50 strips x 1024 */
#define DIM   640
#define SEQ   256
#define NBATCH 16
#define MROWS 4096    /* NBATCH*SEQ */

using bf16 = __hip_bfloat16;
typedef __attribute__((ext_vector_type(8))) short short8;
typedef __attribute__((ext_vector_type(4))) float f32x4;
struct bf16x4 { bf16 a, b, c, d; };

__device__ __forceinline__ void gld_lds16(const void* g, void* l) {
  __builtin_amdgcn_global_load_lds(
      (const __attribute__((address_space(1))) void*)g,
      (__attribute__((address_space(3))) void*)l, 16, 0, 0);
}

#define BAR() asm volatile("s_barrier" ::: "memory")
#define VMC(n) asm volatile("s_waitcnt vmcnt(" #n ")" ::: "memory")
#define VMC0() asm volatile("s_waitcnt vmcnt(0)" ::: "memory")

// ---------------- embed: x = w_embed[idx] + w_pos  -> bf16 ----------------
__global__ void embed_kernel(const int* __restrict__ idx,
                             const float* __restrict__ we,
                             const float* __restrict__ wp,
                             bf16* __restrict__ xb) {
  int row = blockIdx.x;
  int t = row & (SEQ - 1);
  int tok = idx[row];
  const float* src = we + (long)tok * DIM;
  const float* pos = wp + (long)t * DIM;
  for (int d = threadIdx.x * 4; d < DIM; d += blockDim.x * 4) {
    float4 s = *(const float4*)(src + d);
    float4 p = *(const float4*)(pos + d);
    bf16x4 o = { __float2bfloat16(s.x + p.x), __float2bfloat16(s.y + p.y),
                 __float2bfloat16(s.z + p.z), __float2bfloat16(s.w + p.w) };
    *(bf16x4*)(xb + (long)row * DIM + d) = o;
  }
}

// ---------------- f32 -> bf16 convert (x4) with zero tail pad ----------------
__global__ void conv4_kernel(const float* __restrict__ src, bf16* __restrict__ dst,
                             long n_src, long n_dst) {
  long i = ((long)blockIdx.x * blockDim.x + threadIdx.x) * 4;
  long stride = (long)gridDim.x * blockDim.x * 4;
  for (; i < n_dst; i += stride) {
    float4 v = (i < n_src) ? *(const float4*)(src + i) : make_float4(0.f, 0.f, 0.f, 0.f);
    bf16x4 o = { __float2bfloat16(v.x), __float2bfloat16(v.y),
                 __float2bfloat16(v.z), __float2bfloat16(v.w) };
    *(bf16x4*)(dst + i) = o;
  }
}

// ---------------- causal softmax: scores f32 -> P bf16 ----------------
__global__ void softmax_kernel(const float* __restrict__ sc, bf16* __restrict__ p) {
  int wid = threadIdx.x >> 6, lane = threadIdx.x & 63;
  int row = blockIdx.x * 4 + wid;
  int t = row & (SEQ - 1);
  const float* srow = sc + (long)row * SEQ;
  const float rsc = 0.03952847075210474f;  // 1/sqrt(640)
  float v[4];
  float mx = -1e30f;
#pragma unroll
  for (int i = 0; i < 4; ++i) {
    int s = lane + 64 * i;
    v[i] = (s <= t) ? srow[s] * rsc : -1e30f;
    mx = fmaxf(mx, v[i]);
  }
#pragma unroll
  for (int off = 32; off; off >>= 1) mx = fmaxf(mx, __shfl_xor(mx, off, 64));
  float sum = 0.f;
#pragma unroll
  for (int i = 0; i < 4; ++i) {
    int s = lane + 64 * i;
    v[i] = (s <= t) ? __expf(v[i] - mx) : 0.f;
    sum += v[i];
  }
#pragma unroll
  for (int off = 32; off; off >>= 1) sum += __shfl_xor(sum, off, 64);
  float inv = 1.f / sum;
#pragma unroll
  for (int i = 0; i < 4; ++i)
    p[(long)row * SEQ + lane + 64 * i] = __float2bfloat16(v[i] * inv);
}

// ========= 128x128 GEMM, 2-slot depth-1 pipeline (r5 config) =========
// TRV=true (bf16 path only): write C transposed per batch -> vT[b][e][t].
template <int NT, typename OUT_T, bool BIAS, bool TRV>
__global__ __launch_bounds__(256, 4) void gemm_pipe(
    const bf16* __restrict__ Ag, const bf16* __restrict__ Bg,
    OUT_T* __restrict__ Cg, const float* __restrict__ bias,
    int K, int ldc, int Nstore, long sA, long sB, long sC) {
  __shared__ __align__(16) char lds[32768];   // 2 slots x [A 8KB | B 8KB]
  const int tid = threadIdx.x;
  const int lane = tid & 63, wv = tid >> 6;
  const int lr = lane & 15, h16 = lane >> 4;

  const int tm = blockIdx.x, tn = blockIdx.y, bz = blockIdx.z;
  const bf16* A = Ag + (long)bz * sA + (long)tm * 128 * K;
  const bf16* B = Bg + (long)bz * sB + (long)tn * 128 * K;

  int srcE[2], dstW[2];
#pragma unroll
  for (int j = 0; j < 2; ++j) {
    int d = j * 256 + tid;
    int b = d ^ ((d >> 3) & 3);
    srcE[j] = (b >> 2) * K + (b & 3) * 8;
    dstW[j] = (j * 256 + wv * 64) * 16;
  }
  const bf16* aS0 = A + srcE[0];
  const bf16* aS1 = A + srcE[1];
  const bf16* bS0 = B + srcE[0];
  const bf16* bS1 = B + srcE[1];
  auto STAGE = [&](int slot, int t) {
    int kOff = t * 32;
    gld_lds16(aS0 + kOff, lds + slot + dstW[0]);
    gld_lds16(aS1 + kOff, lds + slot + dstW[1]);
    gld_lds16(bS0 + kOff, lds + slot + 8192 + dstW[0]);
    gld_lds16(bS1 + kOff, lds + slot + 8192 + dstW[1]);
  };

  const int wr = (wv >> 1) * 64, wc = (wv & 1) * 64;
  int aoff[4], boff[4];
#pragma unroll
  for (int m = 0; m < 4; ++m) {
    int La = (wr + m * 16 + lr) * 64 + h16 * 16;
    aoff[m] = La ^ (((La >> 7) & 3) << 4);
    int Lb = (wc + m * 16 + lr) * 64 + h16 * 16;
    boff[m] = 8192 + (Lb ^ (((Lb >> 7) & 3) << 4));
  }

  f32x4 acc[4][4] = {};
  short8 a[4], b[4];

  STAGE(0, 0);
  VMC0();
  BAR();

#pragma unroll 2
  for (int t = 0; t < NT; ++t) {
    const int cur = (t & 1) * 16384;
    if (t + 1 < NT) STAGE(16384 - cur, t + 1);
#pragma unroll
    for (int m = 0; m < 4; ++m) a[m] = *(const short8*)(lds + cur + aoff[m]);
#pragma unroll
    for (int n = 0; n < 4; ++n) b[n] = *(const short8*)(lds + cur + boff[n]);
    __builtin_amdgcn_s_setprio(1);
#pragma unroll
    for (int m = 0; m < 4; ++m)
#pragma unroll
      for (int n = 0; n < 4; ++n)
        acc[m][n] = __builtin_amdgcn_mfma_f32_16x16x32_bf16(a[m], b[n], acc[m][n], 0, 0, 0);
    __builtin_amdgcn_s_setprio(0);
    if (t + 1 < NT) VMC0();
    BAR();
  }

  if constexpr (sizeof(OUT_T) == 4) {
    float* Cf = (float*)Cg + (long)bz * sC;
    float bv[4];
#pragma unroll
    for (int n = 0; n < 4; ++n) {
      int col = tn * 128 + wc + lr + n * 16;
      bv[n] = (BIAS && col < Nstore) ? bias[col] : 0.f;
    }
    char* reg = lds + wv * 8192;
    const int rowL = lane & 31, cb = lane >> 5;
#pragma unroll
    for (int mm = 0; mm < 2; ++mm) {
#pragma unroll
      for (int mp = 0; mp < 2; ++mp)
#pragma unroll
        for (int n = 0; n < 4; ++n) {
          f32x4 v = acc[mm * 2 + mp][n];
          v[0] += bv[n]; v[1] += bv[n]; v[2] += bv[n]; v[3] += bv[n];
          int col = lr + n * 16;
          int rho = mp * 16 + h16 * 4;
          int w = col * 32 + (rho ^ ((col & 7) << 2));
          *(f32x4*)(reg + w * 4) = v;
        }
      const long rowg = tm * 128 + wr + mm * 32 + rowL;
#pragma unroll
      for (int k = 0; k < 8; ++k) {
        f32x4 o;
#pragma unroll
        for (int c = 0; c < 4; ++c) {
          int col = k * 8 + cb * 4 + c;
          int w = col * 32 + (rowL ^ ((col & 7) << 2));
          o[c] = *(const float*)(reg + w * 4);
        }
        int gcol = tn * 128 + wc + k * 8 + cb * 4;
        float* dst = Cf + rowg * (long)ldc + gcol;
        if (gcol + 3 < Nstore) {
          *(f32x4*)dst = o;
        } else {
#pragma unroll
          for (int c = 0; c < 4; ++c)
            if (gcol + c < Nstore) dst[c] = o[c];
        }
      }
    }
  } else {
    OUT_T* C = Cg + (long)bz * sC;
    const int crow0 = tm * 128 + wr + h16 * 4;
    const int ccol0 = tn * 128 + wc + lr;
#pragma unroll
    for (int m = 0; m < 4; ++m)
#pragma unroll
      for (int n = 0; n < 4; ++n) {
        int col = ccol0 + n * 16;
        if (col < Nstore) {
#pragma unroll
          for (int j = 0; j < 4; ++j) {
            long row = crow0 + m * 16 + j;
            if constexpr (TRV) {
              C[((long)(row >> 8) * DIM + col) * SEQ + (row & 255)] =
                  __float2bfloat16(acc[m][n][j]);
            } else {
              C[row * ldc + col] = __float2bfloat16(acc[m][n][j]);
            }
          }
        }
      }
  }
}

// ========= scores: 64x64-tile GEMM, causal tile-skip (r15-verified) =========
__global__ __launch_bounds__(256, 6) void scores64(
    const bf16* __restrict__ qg, const bf16* __restrict__ kg,
    float* __restrict__ sc) {
  const int tm = blockIdx.x, tn = blockIdx.y, bz = blockIdx.z;
  if (tn > tm) return;
  __shared__ __align__(16) char lds[16384];
  const int tid = threadIdx.x;
  const int lane = tid & 63, wv = tid >> 6;
  const int lr = lane & 15, h16 = lane >> 4;

  const bf16* A = qg + (long)bz * SEQ * DIM + (long)tm * 64 * DIM;
  const bf16* B = kg + (long)bz * SEQ * DIM + (long)tn * 64 * DIM;

  int srcE, dstW;
  {
    int d = tid;
    int b = d ^ ((d >> 3) & 3);
    srcE = (b >> 2) * DIM + (b & 3) * 8;
    dstW = (wv * 64) * 16;
  }
  auto STAGE = [&](int slot, int t) {
    int kOff = t * 32;
    gld_lds16(A + srcE + kOff, lds + slot + dstW);
    gld_lds16(B + srcE + kOff, lds + slot + 4096 + dstW);
  };

  const int wm = wv >> 1, wn = wv & 1;
  int aoff[2], boff[2];
#pragma unroll
  for (int m = 0; m < 2; ++m) {
    int La = (wm * 32 + m * 16 + lr) * 64 + h16 * 16;
    aoff[m] = La ^ (((La >> 7) & 3) << 4);
    int Lb = (wn * 32 + m * 16 + lr) * 64 + h16 * 16;
    boff[m] = 4096 + (Lb ^ (((Lb >> 7) & 3) << 4));
  }

  f32x4 acc[2][2] = {};
  short8 a[2], b[2];

  STAGE(0, 0);
  VMC0();
  BAR();

#pragma unroll 2
  for (int t = 0; t < 20; ++t) {
    const int cur = (t & 1) * 8192;
    if (t + 1 < 20) STAGE(8192 - cur, t + 1);
#pragma unroll
    for (int m = 0; m < 2; ++m) a[m] = *(const short8*)(lds + cur + aoff[m]);
#pragma unroll
    for (int n = 0; n < 2; ++n) b[n] = *(const short8*)(lds + cur + boff[n]);
    __builtin_amdgcn_s_setprio(1);
#pragma unroll
    for (int m = 0; m < 2; ++m)
#pragma unroll
      for (int n = 0; n < 2; ++n)
        acc[m][n] = __builtin_amdgcn_mfma_f32_16x16x32_bf16(a[m], b[n], acc[m][n], 0, 0, 0);
    __builtin_amdgcn_s_setprio(0);
    if (t + 1 < 20) VMC0();
    BAR();
  }

  float* S = sc + (long)bz * SEQ * SEQ;
  const int crow0 = tm * 64 + wm * 32 + h16 * 4;
  const int ccol0 = tn * 64 + wn * 32 + lr;
#pragma unroll
  for (int m = 0; m < 2; ++m)
#pragma unroll
    for (int n = 0; n < 2; ++n)
#pragma unroll
      for (int j = 0; j < 4; ++j)
        S[(long)(crow0 + m * 16 + j) * SEQ + ccol0 + n * 16] = acc[m][n][j];
}

// ===== logits GEMM: r2's 8-phase 256x256 schedule, STRIP-MINED over 4 tn =====
// Each block computes a 256x1024 strip = 40 logical K-tiles with the r2
// prefetch chain crossing tile/strip boundaries (B source pointer jumps;
// A sources are strip-invariant). Amortizes r2's boundary cost 4x -- the
// hypothesized cause of r2's 21% MfmaUtil (m201 = same structure, 62% at
// 64 K-tiles). Schedule/LDS layout/swizzle transplanted verbatim from r2
// (refcheck-passed; bank conflicts 0). Slot parity strip-invariant (10 even).
// Once-per-strip cost: epilogue stores drain at the next vmcnt(6) (~1-2us).
__global__ __launch_bounds__(512, 1) void gemm256m(
    const bf16* __restrict__ Ag, const bf16* __restrict__ Bg,
    float* __restrict__ Cg, const float* __restrict__ bias) {
  __shared__ __align__(16) char lds[131072];
  const int tid = threadIdx.x;
  const int lane = tid & 63, wv = tid >> 6;
  const int wm = wv >> 2, wn = wv & 3;
  const int tm = blockIdx.x;        // 0..15
  const int tg = blockIdx.y;        // 0..49 strip-group

  // staging source offsets with st_16x32 swizzle pre-applied (r2 verbatim)
  int e0, e1, du0, du1;
  {
    int L0 = tid * 16;
    int L1 = (512 + tid) * 16;
    int Lp0 = L0 ^ (((L0 >> 9) & 1) << 5);
    int Lp1 = L1 ^ (((L1 >> 9) & 1) << 5);
    e0 = ((Lp0 >> 6) & 127) * DIM + ((Lp0 >> 13) & 1) * 32 + ((Lp0 & 63) >> 1);
    e1 = ((Lp1 >> 6) & 127) * DIM + ((Lp1 >> 13) & 1) * 32 + ((Lp1 & 63) >> 1);
    du0 = (wv << 6) * 16;
    du1 = (512 + (wv << 6)) * 16;
  }
  auto STAGE = [&](int halfBase, const bf16* src) {
    gld_lds16(src + e0, lds + halfBase + du0);
    gld_lds16(src + e1, lds + halfBase + du1);
  };

  const bf16* Ab = Ag + (long)tm * 256 * DIM;
  const long STRIDE = (long)256 * DIM;

  // ds_read addressing (r2 verbatim)
  const int lr = lane & 15, h16 = lane >> 4;
  const int laneOff = (lr * 64 + h16 * 16) ^ ((lr & 8) << 2);
  const int abase = wm * 16384 + laneOff;
  const int bbase = 32768 + (wn >> 1) * 16384 + (wn & 1) * 4096 + laneOff;

  f32x4 acc[8][4] = {};
  short8 a0[2][4], a1[2][4], b[2][4];

#define READ_A(DST, SLOT, MFB)                                                \
  { _Pragma("unroll") for (int ks = 0; ks < 2; ++ks)                          \
    _Pragma("unroll") for (int mf = 0; mf < 4; ++mf)                          \
      DST[ks][mf] = *(const short8*)(lds + (SLOT) + abase + ks * 8192 +       \
                                     ((MFB) + mf) * 1024); }
#define READ_B(SLOT)                                                          \
  { _Pragma("unroll") for (int ks = 0; ks < 2; ++ks)                          \
    _Pragma("unroll") for (int nf = 0; nf < 4; ++nf)                          \
      b[ks][nf] = *(const short8*)(lds + (SLOT) + bbase + ks * 8192 +         \
                                   nf * 1024); }
#define MFMA_G(AARR, KS, ROFF)                                                \
  __builtin_amdgcn_s_setprio(1);                                              \
  { _Pragma("unroll") for (int mf = 0; mf < 4; ++mf)                          \
    _Pragma("unroll") for (int nf = 0; nf < 4; ++nf)                          \
      acc[(ROFF) + mf][nf] = __builtin_amdgcn_mfma_f32_16x16x32_bf16(         \
          AARR[KS][mf], b[KS][nf], acc[(ROFF) + mf][nf], 0, 0, 0); }          \
  __builtin_amdgcn_s_setprio(0);

  const bf16* Bc = Bg + (long)tg * 4 * STRIDE;   // strip 0 base

  // ---- prologue (r2 verbatim): tile0 all 4 halves + tile1 {B0,A0,A1}
  STAGE(0,             Ab);
  STAGE(16384,         Ab + 128 * DIM);
  STAGE(32768,         Bc);
  STAGE(49152,         Bc + 128 * DIM);
  STAGE(65536 + 32768, Bc + 64);
  STAGE(65536 + 0,     Ab + 64);
  STAGE(65536 + 16384, Ab + 128 * DIM + 64);
  VMC(6);
  BAR();

  for (int s = 0; s < 4; ++s) {
    const bf16* Bn = Bc + STRIDE;   // next strip (unused when s==3)
    const bool sNotLast = (s < 3);
#pragma unroll
    for (int T = 0; T < 10; ++T) {
      const int slot = (T & 1) << 16;
      const int nslot = ((T + 1) & 1) << 16;
      // k-offsets for prefetch targets U+1, U+2 (wrap into next strip)
      const int k1 = (T < 9) ? (T + 1) * 64 : 0;           // tile U+1
      const int k2 = (T < 8) ? (T + 2) * 64 : (T - 8) * 64; // tile U+2
      const bf16* B1src = (T < 9) ? Bc : Bn;
      const bf16* B2src = (T < 8) ? Bc : Bn;
      const bool ok1 = sNotLast || (T < 9);
      const bool ok2 = sNotLast || (T < 8);
      // ---- phase 0: read A(mh0)+B; stage B1(U+1)
      READ_A(a0, slot, 0);
      READ_B(slot);
      if (ok1) STAGE(nslot + 49152, B1src + 128 * DIM + k1);
      BAR();
      MFMA_G(a0, 0, 0);
      BAR();
      // ---- phase 1: read A(mh1); stage B0(U+2)
      READ_A(a1, slot, 4);
      if (ok2) STAGE(slot + 32768, B2src + k2);
      BAR();
      MFMA_G(a0, 1, 0);
      BAR();
      // ---- phase 2: stage A0(U+2)
      if (ok2) STAGE(slot + 0, Ab + k2);
      BAR();
      MFMA_G(a1, 0, 4);
      BAR();
      // ---- phase 3: stage A1(U+2); counted vmcnt
      if (ok2) {
        STAGE(slot + 16384, Ab + 128 * DIM + k2);
        VMC(6);
      } else if (ok1) {
        VMC(0);
      }
      BAR();
      MFMA_G(a1, 1, 4);
      BAR();
    }
    // ---- strip epilogue: store 256x256 tile, re-zero acc
    {
      const int rowB = tm * 256 + wm * 128 + h16 * 4;
      const int colB = (tg * 4 + s) * 256 + wn * 64 + lr;
#pragma unroll
      for (int mf = 0; mf < 8; ++mf)
#pragma unroll
        for (int nf = 0; nf < 4; ++nf) {
          int col = colB + nf * 16;
          if (col < VOCAB) {
            float bv = bias[col];
#pragma unroll
            for (int jj = 0; jj < 4; ++jj)
              Cg[(long)(rowB + mf * 16 + jj) * VOCAB + col] = acc[mf][nf][jj] + bv;
          }
          acc[mf][nf] = (f32x4){0.f, 0.f, 0.f, 0.f};
        }
    }
    Bc = Bn;
  }
#undef READ_A
#undef READ_B
#undef MFMA_G
}

extern "C" void kernel_launch(void* const* d_in, const int* in_sizes, int n_in,
                              void* d_out, int out_size, void* d_ws, size_t ws_size,
                              hipStream_t stream) {
  const int*   idx     = (const int*)d_in[0];
  const float* w_embed = (const float*)d_in[1];
  const float* w_pos   = (const float*)d_in[2];
  const float* wq      = (const float*)d_in[3];
  const float* wk      = (const float*)d_in[4];
  const float* wv      = (const float*)d_in[5];
  const float* w_out   = (const float*)d_in[6];
  const float* b_out   = (const float*)d_in[7];
  float* out = (float*)d_out;

  size_t off = 0;
  auto alloc = [&](size_t bytes) {
    void* p = (char*)d_ws + off;
    off += (bytes + 255) & ~(size_t)255;
    return p;
  };
  bf16* x_bf    = (bf16*)alloc((size_t)MROWS * DIM * 2);
  bf16* wqkv_bf = (bf16*)alloc((size_t)3 * DIM * DIM * 2);
  bf16* wout_bf = (bf16*)alloc((size_t)VPAD3 * DIM * 2);
  bf16* qkv     = (bf16*)alloc((size_t)2 * MROWS * DIM * 2);  // q,k
  bf16* vT      = (bf16*)alloc((size_t)NBATCH * DIM * SEQ * 2);
  float* scores = (float*)alloc((size_t)NBATCH * SEQ * SEQ * 4);
  bf16* P       = (bf16*)alloc((size_t)NBATCH * SEQ * SEQ * 2);
  bf16* attn    = (bf16*)alloc((size_t)MROWS * DIM * 2);

  const long QKV_S = (long)MROWS * DIM;
  const long W_S   = (long)DIM * DIM;

  // 1. embed
  embed_kernel<<<MROWS, 256, 0, stream>>>(idx, w_embed, w_pos, x_bf);

  // 2. weight converts (bf16; w_out zero-padded to VPAD3 rows)
  conv4_kernel<<<256, 256, 0, stream>>>(wq, wqkv_bf,           W_S, W_S);
  conv4_kernel<<<256, 256, 0, stream>>>(wk, wqkv_bf + W_S,     W_S, W_S);
  conv4_kernel<<<256, 256, 0, stream>>>(wv, wqkv_bf + 2 * W_S, W_S, W_S);
  conv4_kernel<<<2048, 256, 0, stream>>>(w_out, wout_bf, (long)VOCAB * DIM, (long)VPAD3 * DIM);

  // 3a. q,k = x @ {wq,wk}^T
  gemm_pipe<20, bf16, false, false><<<dim3(MROWS / 128, DIM / 128, 2), 256, 0, stream>>>(
      x_bf, wqkv_bf, qkv, nullptr, DIM, DIM, DIM, 0, W_S, QKV_S);

  // 3b. vT = (x @ wv^T)^T per batch (transpose fused into epilogue)
  gemm_pipe<20, bf16, false, true><<<dim3(MROWS / 128, DIM / 128, 1), 256, 0, stream>>>(
      x_bf, wqkv_bf + 2 * W_S, vT, nullptr, DIM, DIM, DIM, 0, 0, 0);

  // 4. scores[b] = q[b] @ k[b]^T  (64x64 tiles, causal skip)
  scores64<<<dim3(4, 4, NBATCH), 256, 0, stream>>>(qkv, qkv + QKV_S, scores);

  // 5. causal softmax -> P bf16
  softmax_kernel<<<MROWS / 4, 256, 0, stream>>>(scores, P);

  // 6. attn[b] = P[b] @ vT[b]^T
  gemm_pipe<8, bf16, false, false><<<dim3(SEQ / 128, DIM / 128, NBATCH), 256, 0, stream>>>(
      P, vT, attn, nullptr, SEQ, DIM, DIM,
      (long)SEQ * SEQ, (long)DIM * SEQ, (long)SEQ * DIM);

  // 7. logits = attn @ w_out^T + b_out  (strip-mined 8-phase 256^2)
  gemm256m<<<dim3(MROWS / 256, VPAD3 / 1024), 512, 0, stream>>>(attn, wout_bf, out, b_out);
}

// Round 19
// 600.180 us; speedup vs baseline: 1.6970x; 1.6970x over previous
//
#include <hip/hip_runtime.h>
#include <hip/hip_bf16.h>
#include <stdint.h>

#define VOCAB 50257
#define VPAD  50432   /* 394*128 */
#define DIM   640
#define SEQ   256
#define NBATCH 16
#define MROWS 4096    /* NBATCH*SEQ */

using bf16 = __hip_bfloat16;
typedef __attribute__((ext_vector_type(8))) short short8;
typedef __attribute__((ext_vector_type(4))) float f32x4;
struct bf16x4 { bf16 a, b, c, d; };

__device__ __forceinline__ void gld_lds16(const void* g, void* l) {
  __builtin_amdgcn_global_load_lds(
      (const __attribute__((address_space(1))) void*)g,
      (__attribute__((address_space(3))) void*)l, 16, 0, 0);
}

#define BAR() asm volatile("s_barrier" ::: "memory")
#define VMC0() asm volatile("s_waitcnt vmcnt(0)" ::: "memory")

// ---------------- embed: x = w_embed[idx] + w_pos  -> bf16 ----------------
__global__ void embed_kernel(const int* __restrict__ idx,
                             const float* __restrict__ we,
                             const float* __restrict__ wp,
                             bf16* __restrict__ xb) {
  int row = blockIdx.x;
  int t = row & (SEQ - 1);
  int tok = idx[row];
  const float* src = we + (long)tok * DIM;
  const float* pos = wp + (long)t * DIM;
  for (int d = threadIdx.x * 4; d < DIM; d += blockDim.x * 4) {
    float4 s = *(const float4*)(src + d);
    float4 p = *(const float4*)(pos + d);
    bf16x4 o = { __float2bfloat16(s.x + p.x), __float2bfloat16(s.y + p.y),
                 __float2bfloat16(s.z + p.z), __float2bfloat16(s.w + p.w) };
    *(bf16x4*)(xb + (long)row * DIM + d) = o;
  }
}

// ---------------- f32 -> bf16 convert (x4) with zero tail pad ----------------
__global__ void conv4_kernel(const float* __restrict__ src, bf16* __restrict__ dst,
                             long n_src, long n_dst) {
  long i = ((long)blockIdx.x * blockDim.x + threadIdx.x) * 4;
  long stride = (long)gridDim.x * blockDim.x * 4;
  for (; i < n_dst; i += stride) {
    float4 v = (i < n_src) ? *(const float4*)(src + i) : make_float4(0.f, 0.f, 0.f, 0.f);
    bf16x4 o = { __float2bfloat16(v.x), __float2bfloat16(v.y),
                 __float2bfloat16(v.z), __float2bfloat16(v.w) };
    *(bf16x4*)(dst + i) = o;
  }
}

// ---------------- causal softmax: scores f32 -> P bf16 ----------------
__global__ void softmax_kernel(const float* __restrict__ sc, bf16* __restrict__ p) {
  int wid = threadIdx.x >> 6, lane = threadIdx.x & 63;
  int row = blockIdx.x * 4 + wid;
  int t = row & (SEQ - 1);
  const float* srow = sc + (long)row * SEQ;
  const float rsc = 0.03952847075210474f;  // 1/sqrt(640)
  float v[4];
  float mx = -1e30f;
#pragma unroll
  for (int i = 0; i < 4; ++i) {
    int s = lane + 64 * i;
    v[i] = (s <= t) ? srow[s] * rsc : -1e30f;
    mx = fmaxf(mx, v[i]);
  }
#pragma unroll
  for (int off = 32; off; off >>= 1) mx = fmaxf(mx, __shfl_xor(mx, off, 64));
  float sum = 0.f;
#pragma unroll
  for (int i = 0; i < 4; ++i) {
    int s = lane + 64 * i;
    v[i] = (s <= t) ? __expf(v[i] - mx) : 0.f;
    sum += v[i];
  }
#pragma unroll
  for (int off = 32; off; off >>= 1) sum += __shfl_xor(sum, off, 64);
  float inv = 1.f / sum;
#pragma unroll
  for (int i = 0; i < 4; ++i)
    p[(long)row * SEQ + lane + 64 * i] = __float2bfloat16(v[i] * inv);
}

// ========= 128x128 GEMM, 2-slot depth-1 pipeline (r5 config) =========
// TRV=true (bf16 path only): write C transposed per batch -> vT[b][e][t]
// (b = row>>8, t = row&255, e = col), fusing the V-transpose into the epilogue.
template <int NT, typename OUT_T, bool BIAS, bool TRV>
__global__ __launch_bounds__(256, 4) void gemm_pipe(
    const bf16* __restrict__ Ag, const bf16* __restrict__ Bg,
    OUT_T* __restrict__ Cg, const float* __restrict__ bias,
    int K, int ldc, int Nstore, long sA, long sB, long sC) {
  __shared__ __align__(16) char lds[32768];   // 2 slots x [A 8KB | B 8KB]
  const int tid = threadIdx.x;
  const int lane = tid & 63, wv = tid >> 6;
  const int lr = lane & 15, h16 = lane >> 4;

  const int tm = blockIdx.x, tn = blockIdx.y, bz = blockIdx.z;
  const bf16* A = Ag + (long)bz * sA + (long)tm * 128 * K;
  const bf16* B = Bg + (long)bz * sB + (long)tn * 128 * K;

  int srcE[2], dstW[2];
#pragma unroll
  for (int j = 0; j < 2; ++j) {
    int d = j * 256 + tid;
    int b = d ^ ((d >> 3) & 3);
    srcE[j] = (b >> 2) * K + (b & 3) * 8;
    dstW[j] = (j * 256 + wv * 64) * 16;
  }
  const bf16* aS0 = A + srcE[0];
  const bf16* aS1 = A + srcE[1];
  const bf16* bS0 = B + srcE[0];
  const bf16* bS1 = B + srcE[1];
  auto STAGE = [&](int slot, int t) {
    int kOff = t * 32;
    gld_lds16(aS0 + kOff, lds + slot + dstW[0]);
    gld_lds16(aS1 + kOff, lds + slot + dstW[1]);
    gld_lds16(bS0 + kOff, lds + slot + 8192 + dstW[0]);
    gld_lds16(bS1 + kOff, lds + slot + 8192 + dstW[1]);
  };

  const int wr = (wv >> 1) * 64, wc = (wv & 1) * 64;
  int aoff[4], boff[4];
#pragma unroll
  for (int m = 0; m < 4; ++m) {
    int La = (wr + m * 16 + lr) * 64 + h16 * 16;
    aoff[m] = La ^ (((La >> 7) & 3) << 4);
    int Lb = (wc + m * 16 + lr) * 64 + h16 * 16;
    boff[m] = 8192 + (Lb ^ (((Lb >> 7) & 3) << 4));
  }

  f32x4 acc[4][4] = {};
  short8 a[4], b[4];

  STAGE(0, 0);
  VMC0();
  BAR();

#pragma unroll 2
  for (int t = 0; t < NT; ++t) {
    const int cur = (t & 1) * 16384;
    if (t + 1 < NT) STAGE(16384 - cur, t + 1);
#pragma unroll
    for (int m = 0; m < 4; ++m) a[m] = *(const short8*)(lds + cur + aoff[m]);
#pragma unroll
    for (int n = 0; n < 4; ++n) b[n] = *(const short8*)(lds + cur + boff[n]);
    __builtin_amdgcn_s_setprio(1);
#pragma unroll
    for (int m = 0; m < 4; ++m)
#pragma unroll
      for (int n = 0; n < 4; ++n)
        acc[m][n] = __builtin_amdgcn_mfma_f32_16x16x32_bf16(a[m], b[n], acc[m][n], 0, 0, 0);
    __builtin_amdgcn_s_setprio(0);
    if (t + 1 < NT) VMC0();
    BAR();
  }

  if constexpr (sizeof(OUT_T) == 4) {
    // wide-store epilogue via per-wave LDS transpose (cached stores)
    float* Cf = (float*)Cg + (long)bz * sC;
    float bv[4];
#pragma unroll
    for (int n = 0; n < 4; ++n) {
      int col = tn * 128 + wc + lr + n * 16;
      bv[n] = (BIAS && col < Nstore) ? bias[col] : 0.f;
    }
    char* reg = lds + wv * 8192;
    const int rowL = lane & 31, cb = lane >> 5;
#pragma unroll
    for (int mm = 0; mm < 2; ++mm) {
#pragma unroll
      for (int mp = 0; mp < 2; ++mp)
#pragma unroll
        for (int n = 0; n < 4; ++n) {
          f32x4 v = acc[mm * 2 + mp][n];
          v[0] += bv[n]; v[1] += bv[n]; v[2] += bv[n]; v[3] += bv[n];
          int col = lr + n * 16;
          int rho = mp * 16 + h16 * 4;
          int w = col * 32 + (rho ^ ((col & 7) << 2));
          *(f32x4*)(reg + w * 4) = v;
        }
      const long rowg = tm * 128 + wr + mm * 32 + rowL;
#pragma unroll
      for (int k = 0; k < 8; ++k) {
        f32x4 o;
#pragma unroll
        for (int c = 0; c < 4; ++c) {
          int col = k * 8 + cb * 4 + c;
          int w = col * 32 + (rowL ^ ((col & 7) << 2));
          o[c] = *(const float*)(reg + w * 4);
        }
        int gcol = tn * 128 + wc + k * 8 + cb * 4;
        float* dst = Cf + rowg * (long)ldc + gcol;
        if (gcol + 3 < Nstore) {
          *(f32x4*)dst = o;
        } else {
#pragma unroll
          for (int c = 0; c < 4; ++c)
            if (gcol + c < Nstore) dst[c] = o[c];
        }
      }
    }
  } else {
    OUT_T* C = Cg + (long)bz * sC;
    const int crow0 = tm * 128 + wr + h16 * 4;
    const int ccol0 = tn * 128 + wc + lr;
#pragma unroll
    for (int m = 0; m < 4; ++m)
#pragma unroll
      for (int n = 0; n < 4; ++n) {
        int col = ccol0 + n * 16;
        if (col < Nstore) {
#pragma unroll
          for (int j = 0; j < 4; ++j) {
            long row = crow0 + m * 16 + j;
            if constexpr (TRV) {
              // vT[b][e][t]: fused V transpose
              C[((long)(row >> 8) * DIM + col) * SEQ + (row & 255)] =
                  __float2bfloat16(acc[m][n][j]);
            } else {
              C[row * ldc + col] = __float2bfloat16(acc[m][n][j]);
            }
          }
        }
      }
  }
}

// ========= scores: 64x64-tile GEMM, causal tile-skip (r15-verified) =========
__global__ __launch_bounds__(256, 6) void scores64(
    const bf16* __restrict__ qg, const bf16* __restrict__ kg,
    float* __restrict__ sc) {
  const int tm = blockIdx.x, tn = blockIdx.y, bz = blockIdx.z;
  if (tn > tm) return;   // fully-masked causal tile
  __shared__ __align__(16) char lds[16384];   // 2 slots x [A 4KB | B 4KB]
  const int tid = threadIdx.x;
  const int lane = tid & 63, wv = tid >> 6;
  const int lr = lane & 15, h16 = lane >> 4;

  const bf16* A = qg + (long)bz * SEQ * DIM + (long)tm * 64 * DIM;
  const bf16* B = kg + (long)bz * SEQ * DIM + (long)tn * 64 * DIM;

  int srcE, dstW;
  {
    int d = tid;
    int b = d ^ ((d >> 3) & 3);
    srcE = (b >> 2) * DIM + (b & 3) * 8;
    dstW = (wv * 64) * 16;
  }
  auto STAGE = [&](int slot, int t) {
    int kOff = t * 32;
    gld_lds16(A + srcE + kOff, lds + slot + dstW);
    gld_lds16(B + srcE + kOff, lds + slot + 4096 + dstW);
  };

  const int wm = wv >> 1, wn = wv & 1;
  int aoff[2], boff[2];
#pragma unroll
  for (int m = 0; m < 2; ++m) {
    int La = (wm * 32 + m * 16 + lr) * 64 + h16 * 16;
    aoff[m] = La ^ (((La >> 7) & 3) << 4);
    int Lb = (wn * 32 + m * 16 + lr) * 64 + h16 * 16;
    boff[m] = 4096 + (Lb ^ (((Lb >> 7) & 3) << 4));
  }

  f32x4 acc[2][2] = {};
  short8 a[2], b[2];

  STAGE(0, 0);
  VMC0();
  BAR();

#pragma unroll 2
  for (int t = 0; t < 20; ++t) {
    const int cur = (t & 1) * 8192;
    if (t + 1 < 20) STAGE(8192 - cur, t + 1);
#pragma unroll
    for (int m = 0; m < 2; ++m) a[m] = *(const short8*)(lds + cur + aoff[m]);
#pragma unroll
    for (int n = 0; n < 2; ++n) b[n] = *(const short8*)(lds + cur + boff[n]);
    __builtin_amdgcn_s_setprio(1);
#pragma unroll
    for (int m = 0; m < 2; ++m)
#pragma unroll
      for (int n = 0; n < 2; ++n)
        acc[m][n] = __builtin_amdgcn_mfma_f32_16x16x32_bf16(a[m], b[n], acc[m][n], 0, 0, 0);
    __builtin_amdgcn_s_setprio(0);
    if (t + 1 < 20) VMC0();
    BAR();
  }

  float* S = sc + (long)bz * SEQ * SEQ;
  const int crow0 = tm * 64 + wm * 32 + h16 * 4;
  const int ccol0 = tn * 64 + wn * 32 + lr;
#pragma unroll
  for (int m = 0; m < 2; ++m)
#pragma unroll
    for (int n = 0; n < 2; ++n)
#pragma unroll
      for (int j = 0; j < 4; ++j)
        S[(long)(crow0 + m * 16 + j) * SEQ + ccol0 + n * 16] = acc[m][n][j];
}

// ========= logits GEMM: r9's gemm8 VERBATIM (best measured: 485-490us) =========
// 128x128 tile, 8 waves (2Mx4N, 64x32 each, acc[4][2]=32 regs), BK=32,
// depth-1 2-slot ring, tm-fastest grid, ~68% occupancy, 0 bank conflicts.
// Structural ceiling for K=640 established over r1-r18; falsified axes:
// depth 1/2/4, barrier-free, TLP 45-68%, staged bytes 2-4x, FETCH 272MB-1GB,
// BK 32/64, write locality/span/nt-stores, 8-phase (r2, r18 strip-mined),
// f32-fused staging (r16: bank conflicts).
__global__ __launch_bounds__(512, 6) void gemm8(
    const bf16* __restrict__ Ag, const bf16* __restrict__ Bg,
    float* __restrict__ Cg, const float* __restrict__ bias) {
  __shared__ __align__(16) char lds[32768];   // 2 slots x [A 8KB | B 8KB]
  const int tid = threadIdx.x;
  const int lane = tid & 63, wv = tid >> 6;
  const int lr = lane & 15, h16 = lane >> 4;

  const int tm = blockIdx.x, tn = blockIdx.y;
  const bf16* A = Ag + (long)tm * 128 * DIM;
  const bf16* B = Bg + (long)tn * 128 * DIM;

  int srcE, dstW;
  {
    int d = tid;
    int b = d ^ ((d >> 3) & 3);
    srcE = (b >> 2) * DIM + (b & 3) * 8;
    dstW = (wv * 64) * 16;
  }
  const bf16* aS = A + srcE;
  const bf16* bS = B + srcE;
  auto STAGE = [&](int slot, int t) {
    int kOff = t * 32;
    gld_lds16(aS + kOff, lds + slot + dstW);
    gld_lds16(bS + kOff, lds + slot + 8192 + dstW);
  };

  const int wr = (wv >> 2) * 64, wc = (wv & 3) * 32;
  int aoff[4], boff[2];
#pragma unroll
  for (int m = 0; m < 4; ++m) {
    int La = (wr + m * 16 + lr) * 64 + h16 * 16;
    aoff[m] = La ^ (((La >> 7) & 3) << 4);
  }
#pragma unroll
  for (int n = 0; n < 2; ++n) {
    int Lb = (wc + n * 16 + lr) * 64 + h16 * 16;
    boff[n] = 8192 + (Lb ^ (((Lb >> 7) & 3) << 4));
  }

  f32x4 acc[4][2] = {};
  short8 a[4], b[2];

  STAGE(0, 0);
  VMC0();
  BAR();

#pragma unroll 2
  for (int t = 0; t < 20; ++t) {
    const int cur = (t & 1) * 16384;
    if (t + 1 < 20) STAGE(16384 - cur, t + 1);
#pragma unroll
    for (int m = 0; m < 4; ++m) a[m] = *(const short8*)(lds + cur + aoff[m]);
#pragma unroll
    for (int n = 0; n < 2; ++n) b[n] = *(const short8*)(lds + cur + boff[n]);
    __builtin_amdgcn_s_setprio(1);
#pragma unroll
    for (int m = 0; m < 4; ++m)
#pragma unroll
      for (int n = 0; n < 2; ++n)
        acc[m][n] = __builtin_amdgcn_mfma_f32_16x16x32_bf16(a[m], b[n], acc[m][n], 0, 0, 0);
    __builtin_amdgcn_s_setprio(0);
    if (t + 1 < 20) VMC0();
    BAR();
  }

  const int crow0 = tm * 128 + wr + h16 * 4;
  const int ccol0 = tn * 128 + wc + lr;
  float bv[2];
#pragma unroll
  for (int n = 0; n < 2; ++n) {
    int col = ccol0 + n * 16;
    bv[n] = (col < VOCAB) ? bias[col] : 0.f;
  }
#pragma unroll
  for (int m = 0; m < 4; ++m)
#pragma unroll
    for (int n = 0; n < 2; ++n) {
      int col = ccol0 + n * 16;
      if (col < VOCAB) {
#pragma unroll
        for (int j = 0; j < 4; ++j)
          Cg[(long)(crow0 + m * 16 + j) * VOCAB + col] = acc[m][n][j] + bv[n];
      }
    }
}

extern "C" void kernel_launch(void* const* d_in, const int* in_sizes, int n_in,
                              void* d_out, int out_size, void* d_ws, size_t ws_size,
                              hipStream_t stream) {
  const int*   idx     = (const int*)d_in[0];
  const float* w_embed = (const float*)d_in[1];
  const float* w_pos   = (const float*)d_in[2];
  const float* wq      = (const float*)d_in[3];
  const float* wk      = (const float*)d_in[4];
  const float* wv      = (const float*)d_in[5];
  const float* w_out   = (const float*)d_in[6];
  const float* b_out   = (const float*)d_in[7];
  float* out = (float*)d_out;

  size_t off = 0;
  auto alloc = [&](size_t bytes) {
    void* p = (char*)d_ws + off;
    off += (bytes + 255) & ~(size_t)255;
    return p;
  };
  bf16* x_bf    = (bf16*)alloc((size_t)MROWS * DIM * 2);
  bf16* wqkv_bf = (bf16*)alloc((size_t)3 * DIM * DIM * 2);
  bf16* wout_bf = (bf16*)alloc((size_t)VPAD * DIM * 2);
  bf16* qkv     = (bf16*)alloc((size_t)2 * MROWS * DIM * 2);  // q,k
  bf16* vT      = (bf16*)alloc((size_t)NBATCH * DIM * SEQ * 2);
  float* scores = (float*)alloc((size_t)NBATCH * SEQ * SEQ * 4);
  bf16* P       = (bf16*)alloc((size_t)NBATCH * SEQ * SEQ * 2);
  bf16* attn    = (bf16*)alloc((size_t)MROWS * DIM * 2);

  const long QKV_S = (long)MROWS * DIM;
  const long W_S   = (long)DIM * DIM;

  // 1. embed
  embed_kernel<<<MROWS, 256, 0, stream>>>(idx, w_embed, w_pos, x_bf);

  // 2. weight converts (bf16; w_out zero-padded to VPAD rows)
  conv4_kernel<<<256, 256, 0, stream>>>(wq, wqkv_bf,           W_S, W_S);
  conv4_kernel<<<256, 256, 0, stream>>>(wk, wqkv_bf + W_S,     W_S, W_S);
  conv4_kernel<<<256, 256, 0, stream>>>(wv, wqkv_bf + 2 * W_S, W_S, W_S);
  conv4_kernel<<<2048, 256, 0, stream>>>(w_out, wout_bf, (long)VOCAB * DIM, (long)VPAD * DIM);

  // 3a. q,k = x @ {wq,wk}^T   (K=640 -> NT=20)
  gemm_pipe<20, bf16, false, false><<<dim3(MROWS / 128, DIM / 128, 2), 256, 0, stream>>>(
      x_bf, wqkv_bf, qkv, nullptr, DIM, DIM, DIM, 0, W_S, QKV_S);

  // 3b. vT = (x @ wv^T)^T per batch  (transpose fused into epilogue)
  gemm_pipe<20, bf16, false, true><<<dim3(MROWS / 128, DIM / 128, 1), 256, 0, stream>>>(
      x_bf, wqkv_bf + 2 * W_S, vT, nullptr, DIM, DIM, DIM, 0, 0, 0);

  // 4. scores[b] = q[b] @ k[b]^T  (64x64 tiles, causal skip)
  scores64<<<dim3(4, 4, NBATCH), 256, 0, stream>>>(qkv, qkv + QKV_S, scores);

  // 5. causal softmax -> P bf16
  softmax_kernel<<<MROWS / 4, 256, 0, stream>>>(scores, P);

  // 6. attn[b] = P[b] @ vT[b]^T  (K=256 -> NT=8)
  gemm_pipe<8, bf16, false, false><<<dim3(SEQ / 128, DIM / 128, NBATCH), 256, 0, stream>>>(
      P, vT, attn, nullptr, SEQ, DIM, DIM,
      (long)SEQ * SEQ, (long)DIM * SEQ, (long)SEQ * DIM);

  // 7. logits = attn @ w_out^T + b_out  (r9 gemm8: best-measured config)
  gemm8<<<dim3(MROWS / 128, VPAD / 128), 512, 0, stream>>>(attn, wout_bf, out, b_out);
}